// Round 1
// baseline (4174.868 us; speedup 1.0000x reference)
//
#include <hip/hip_runtime.h>
#include <hip/hip_bf16.h>
#include <cstdint>

// Problem constants (match reference setup_inputs; reference hardcodes them too)
#define N0c 200000
#define N1c 100000
#define N2c 80000
#define Fc  32
#define K5c 125
#define K3c 27
#define M1c 20000
#define M2c 20000
#define M3c 30000
#define M4c 20000
#define EPSc 1e-5f

// ---------------------------------------------------------------------------
// Sparse conv: out[out_idx[k,m]] += feats[in_idx[k,m]] @ W[k]
// grid.y = k, grid.x = m-chunks, grid.z = cout tile. Block = 256 threads.
// Each thread handles one (pair, cout-in-tile); W[k] tile staged in LDS.
// ---------------------------------------------------------------------------
template <int CIN, int COUT, int CTILE, bool RELU_GATHER>
__global__ __launch_bounds__(256) void sparse_conv_kernel(
    const float* __restrict__ feats,
    const float* __restrict__ W,      // [K, CIN, COUT]
    const int* __restrict__ in_idx,   // [K, M]
    const int* __restrict__ out_idx,  // [K, M]
    float* __restrict__ out,          // [n_out, COUT]
    int M)
{
    constexpr int PPB = 256 / CTILE;   // pairs per block-iteration
    const int k  = blockIdx.y;
    const int ct = blockIdx.z;

    __shared__ float Wl[CIN][CTILE];
    {
        const float* Wk = W + (size_t)k * CIN * COUT + (size_t)ct * CTILE;
        for (int i = threadIdx.x; i < CIN * CTILE; i += 256) {
            int j = i / CTILE, c = i % CTILE;
            Wl[j][c] = Wk[(size_t)j * COUT + c];
        }
    }
    __syncthreads();

    const int pl = threadIdx.x / CTILE;   // pair slot within block
    const int c  = threadIdx.x % CTILE;   // cout within tile
    const int* iin  = in_idx  + (size_t)k * M;
    const int* iout = out_idx + (size_t)k * M;

    for (int base = blockIdx.x * PPB; base < M; base += gridDim.x * PPB) {
        int p = base + pl;
        if (p < M) {
            int in = iin[p];
            int o  = iout[p];
            float acc = 0.f;
            if constexpr (CIN % 4 == 0) {
                const float4* fr4 = reinterpret_cast<const float4*>(feats + (size_t)in * CIN);
                #pragma unroll
                for (int j4 = 0; j4 < CIN / 4; ++j4) {
                    float4 v = fr4[j4];
                    if (RELU_GATHER) {
                        v.x = fmaxf(v.x, 0.f); v.y = fmaxf(v.y, 0.f);
                        v.z = fmaxf(v.z, 0.f); v.w = fmaxf(v.w, 0.f);
                    }
                    acc += v.x * Wl[4 * j4 + 0][c];
                    acc += v.y * Wl[4 * j4 + 1][c];
                    acc += v.z * Wl[4 * j4 + 2][c];
                    acc += v.w * Wl[4 * j4 + 3][c];
                }
            } else {
                #pragma unroll
                for (int j = 0; j < CIN; ++j) {
                    float v = feats[(size_t)in * CIN + j];
                    if (RELU_GATHER) v = fmaxf(v, 0.f);
                    acc += v * Wl[j][c];
                }
            }
            atomicAdd(&out[(size_t)o * COUT + (size_t)ct * CTILE + c], acc);
        }
    }
}

// ---------------------------------------------------------------------------
// BN stats: sums[0..C-1] = sum, sums[C..2C-1] = sumsq  (caller zero-inits)
// Requires 256 % C == 0.
// ---------------------------------------------------------------------------
template <int C>
__global__ __launch_bounds__(256) void bn_stats_kernel(
    const float* __restrict__ x, int n, float* __restrict__ sums)
{
    float s = 0.f, s2 = 0.f;
    size_t total = (size_t)n * C;
    size_t stride = (size_t)gridDim.x * 256;
    for (size_t i = (size_t)blockIdx.x * 256 + threadIdx.x; i < total; i += stride) {
        float v = x[i];
        s += v;
        s2 += v * v;
    }
    __shared__ float ls[256], ls2[256];
    ls[threadIdx.x] = s;
    ls2[threadIdx.x] = s2;
    __syncthreads();
    for (int off = 128; off >= C; off >>= 1) {
        if (threadIdx.x < (unsigned)off) {
            ls[threadIdx.x]  += ls[threadIdx.x + off];
            ls2[threadIdx.x] += ls2[threadIdx.x + off];
        }
        __syncthreads();
    }
    if (threadIdx.x < C) {
        atomicAdd(&sums[threadIdx.x], ls[threadIdx.x]);
        atomicAdd(&sums[C + threadIdx.x], ls2[threadIdx.x]);
    }
}

// ---------------------------------------------------------------------------
// BN apply + ReLU, in place. mean/var from sums; population variance.
// ---------------------------------------------------------------------------
template <int C>
__global__ __launch_bounds__(256) void bn_apply_relu_kernel(
    float* __restrict__ x, int n,
    const float* __restrict__ sums,
    const float* __restrict__ g, const float* __restrict__ b)
{
    const int c = threadIdx.x % C;
    const float inv_n = 1.0f / (float)n;
    float mean = sums[c] * inv_n;
    float var  = sums[C + c] * inv_n - mean * mean;
    float scale = g[c] * rsqrtf(var + EPSc);
    float shift = b[c] - mean * scale;
    size_t total = (size_t)n * C;
    size_t stride = (size_t)gridDim.x * 256;
    for (size_t i = (size_t)blockIdx.x * 256 + threadIdx.x; i < total; i += stride) {
        x[i] = fmaxf(x[i] * scale + shift, 0.f);
    }
}

// ---------------------------------------------------------------------------
template <int CIN, int COUT, int CTILE, bool RG>
static void launch_conv(const float* feats, const float* W,
                        const int* iin, const int* iout, float* out,
                        int M, int K, hipStream_t s)
{
    constexpr int PPB = 256 / CTILE;
    constexpr int ITERS = 8;
    int gx = (M + PPB * ITERS - 1) / (PPB * ITERS);
    dim3 grid(gx, K, COUT / CTILE);
    hipLaunchKernelGGL((sparse_conv_kernel<CIN, COUT, CTILE, RG>),
                       grid, dim3(256), 0, s, feats, W, iin, iout, out, M);
}

template <int C>
static void launch_bn(float* x, int n, float* sums,
                      const float* g, const float* b, hipStream_t s)
{
    hipLaunchKernelGGL((bn_stats_kernel<C>), dim3(512), dim3(256), 0, s, x, n, sums);
    hipLaunchKernelGGL((bn_apply_relu_kernel<C>), dim3(2048), dim3(256), 0, s, x, n, sums, g, b);
}

extern "C" void kernel_launch(void* const* d_in, const int* in_sizes, int n_in,
                              void* d_out, int out_size, void* d_ws, size_t ws_size,
                              hipStream_t stream)
{
    const float* x_feats = (const float*)d_in[0];
    const float* w1a = (const float*)d_in[1];
    const float* w1b = (const float*)d_in[2];
    const float* w1c = (const float*)d_in[3];
    const float* w2  = (const float*)d_in[4];
    const float* w3a = (const float*)d_in[5];
    const float* w3b = (const float*)d_in[6];
    const float* bn1b_g = (const float*)d_in[7];
    const float* bn1b_b = (const float*)d_in[8];
    const float* bn1c_g = (const float*)d_in[9];
    const float* bn1c_b = (const float*)d_in[10];
    const float* bn3a_g = (const float*)d_in[11];
    const float* bn3a_b = (const float*)d_in[12];
    const float* bn3b_g = (const float*)d_in[13];
    const float* bn3b_b = (const float*)d_in[14];
    const int* km1a_in  = (const int*)d_in[15];
    const int* km1a_out = (const int*)d_in[16];
    const int* km1b_in  = (const int*)d_in[17];
    const int* km1b_out = (const int*)d_in[18];
    const int* km1c_in  = (const int*)d_in[19];
    const int* km1c_out = (const int*)d_in[20];
    const int* km2_in   = (const int*)d_in[21];
    const int* km2_out  = (const int*)d_in[22];
    const int* km3a_in  = (const int*)d_in[23];
    const int* km3a_out = (const int*)d_in[24];
    const int* km3b_in  = (const int*)d_in[25];
    const int* km3b_out = (const int*)d_in[26];

    float* out  = (float*)d_out;
    float* x_e1 = out;                        // [N1, 32]
    float* x_e2 = out + (size_t)N1c * 32;     // [N2, 256]

    float* ws  = (float*)d_ws;
    float* h1    = ws;                               // [N1, 32]
    float* h2    = h1  + (size_t)N1c * 32;           // [N1, 32]
    float* h2b   = h2  + (size_t)N1c * 32;           // [N2, 64]
    float* h3    = h2b + (size_t)N2c * 64;           // [N2, 128]
    float* stats = h3  + (size_t)N2c * 128;          // 4 x 512 floats
    size_t ws_floats = (size_t)N1c * 64 + (size_t)N2c * 192 + 4 * 512;

    // Zero accumulators (ws and out are poisoned before every call)
    hipMemsetAsync(d_ws, 0, ws_floats * sizeof(float), stream);
    hipMemsetAsync(d_out, 0, (size_t)out_size * sizeof(float), stream);

    float* st1b = stats;
    float* st1c = stats + 512;
    float* st3a = stats + 1024;
    float* st3b = stats + 1536;

    // enc1: conv(1->32, K=125) + ReLU (ReLU fused into next gather)
    launch_conv<1, 32, 32, false>(x_feats, w1a, km1a_in, km1a_out, h1, M1c, K5c, stream);
    // conv(32->32, K=125) + BN + ReLU
    launch_conv<32, 32, 32, true>(h1, w1b, km1b_in, km1b_out, h2, M2c, K5c, stream);
    launch_bn<32>(h2, N1c, st1b, bn1b_g, bn1b_b, stream);
    // conv(32->32, K=125) + BN + ReLU -> x_e1 (in d_out)
    launch_conv<32, 32, 32, false>(h2, w1c, km1c_in, km1c_out, x_e1, M2c, K5c, stream);
    launch_bn<32>(x_e1, N1c, st1c, bn1c_g, bn1c_b, stream);
    // conv2: conv(32->64, K=27), no activation
    launch_conv<32, 64, 64, false>(x_e1, w2, km2_in, km2_out, h2b, M3c, K3c, stream);
    // enc2: conv(64->128, K=27) + BN + ReLU
    launch_conv<64, 128, 128, false>(h2b, w3a, km3a_in, km3a_out, h3, M4c, K3c, stream);
    launch_bn<128>(h3, N2c, st3a, bn3a_g, bn3a_b, stream);
    // conv(128->256, K=27) + BN + ReLU -> x_e2 (in d_out)
    launch_conv<128, 256, 64, false>(h3, w3b, km3b_in, km3b_out, x_e2, M4c, K3c, stream);
    launch_bn<256>(x_e2, N2c, st3b, bn3b_g, bn3b_b, stream);
}

// Round 3
// 2804.777 us; speedup vs baseline: 1.4885x; 1.4885x over previous
//
#include <hip/hip_runtime.h>
#include <cstdint>
#include <algorithm>

// ---------------- problem constants ----------------
#define N1c 100000
#define N2c 80000
#define EPSc 1e-5f

// ---------------- CSR build (per layer-chunk) ----------------
__global__ __launch_bounds__(256) void rank_kernel(
    const int* __restrict__ out_idx, int* __restrict__ rank,
    int* __restrict__ bins, int E)
{
    for (int e = blockIdx.x * 256 + threadIdx.x; e < E; e += gridDim.x * 256)
        rank[e] = atomicAdd(&bins[out_idx[e]], 1);
}

__global__ __launch_bounds__(256) void scan1(
    const int* __restrict__ bins, int* __restrict__ ptr,
    int* __restrict__ bsums, int n)
{
    __shared__ int lds[256];
    int base = blockIdx.x * 1024;
    int v[4]; int t = 0;
    #pragma unroll
    for (int i = 0; i < 4; ++i) {
        int idx = base + threadIdx.x * 4 + i;
        v[i] = idx < n ? bins[idx] : 0;
        t += v[i];
    }
    lds[threadIdx.x] = t; __syncthreads();
    for (int off = 1; off < 256; off <<= 1) {
        int x = threadIdx.x >= off ? lds[threadIdx.x - off] : 0;
        __syncthreads();
        lds[threadIdx.x] += x;
        __syncthreads();
    }
    int run = lds[threadIdx.x] - t;   // exclusive base for this thread
    if (threadIdx.x == 255) bsums[blockIdx.x] = lds[255];
    #pragma unroll
    for (int i = 0; i < 4; ++i) {
        int idx = base + threadIdx.x * 4 + i;
        if (idx < n) ptr[idx] = run;
        run += v[i];
    }
}

__global__ __launch_bounds__(256) void scan2(int* __restrict__ bsums, int nb)
{
    __shared__ int lds[256];
    __shared__ int carry;
    if (threadIdx.x == 0) carry = 0;
    __syncthreads();
    for (int base = 0; base < nb; base += 256) {
        int i = base + threadIdx.x;
        int v = i < nb ? bsums[i] : 0;
        lds[threadIdx.x] = v; __syncthreads();
        for (int off = 1; off < 256; off <<= 1) {
            int x = threadIdx.x >= off ? lds[threadIdx.x - off] : 0;
            __syncthreads();
            lds[threadIdx.x] += x;
            __syncthreads();
        }
        if (i < nb) bsums[i] = lds[threadIdx.x] - v + carry;
        __syncthreads();
        if (threadIdx.x == 0) carry += lds[255];
        __syncthreads();
    }
}

__global__ __launch_bounds__(256) void scan3(
    int* __restrict__ ptr, const int* __restrict__ bsums, int n)
{
    int idx = blockIdx.x * 1024 + threadIdx.x * 4;
    int add = bsums[blockIdx.x];
    #pragma unroll
    for (int i = 0; i < 4; ++i)
        if (idx + i < n) ptr[idx + i] += add;
}

// ---------------- Phase A: conv1a special (CIN=1) ----------------
// iin/iout/rank/W pre-offset to chunk base; k = blockIdx.y within chunk.
__global__ __launch_bounds__(256) void phaseA_1a(
    const float* __restrict__ x, const float* __restrict__ W, // [qc,32]
    const int* __restrict__ iin, const int* __restrict__ iout,
    const int* __restrict__ ptr, const int* __restrict__ rank,
    float* __restrict__ contrib, int M)
{
    const int k = blockIdx.y;
    const int c4 = (threadIdx.x % 8) * 4;
    const int ps = threadIdx.x / 8;     // 32 pair slots per iter
    float4 w4 = *(const float4*)(W + (size_t)k * 32 + c4);
    const int* ii = iin  + (size_t)k * M;
    const int* io = iout + (size_t)k * M;
    const int* rk = rank + (size_t)k * M;
    for (int base = blockIdx.x * 32; base < M; base += gridDim.x * 32) {
        int p = base + ps;
        if (p < M) {
            float v = x[ii[p]];
            int s = ptr[io[p]] + rk[p];
            float4 o4; o4.x = v * w4.x; o4.y = v * w4.y; o4.z = v * w4.z; o4.w = v * w4.w;
            *(float4*)(contrib + (size_t)s * 32 + c4) = o4;
        }
    }
}

// ---------------- Phase A: tiled gather-GEMM, sorted plain-store scatter ----
// thread tile = 4 pairs x 4 couts; W[k] tile + transposed feats staged in LDS.
template <int CIN, int COUT, int CTILE>
__global__ __launch_bounds__(256) void phaseA_tiled(
    const float* __restrict__ feats, const float* __restrict__ W, // [qc,CIN,COUT]
    const int* __restrict__ in_idx, const int* __restrict__ out_idx,
    const int* __restrict__ ptr, const int* __restrict__ rank,
    float* __restrict__ contrib, int M)
{
    constexpr int PP   = 4096 / CTILE;   // pairs per chunk
    constexpr int NCG  = CTILE / 4;      // cout groups
    constexpr int LOADERS = 256 / PP;    // feat-row loaders per pair
    constexpr int FTS  = PP + 4;         // padded (16B-aligned) ft stride
    constexpr int NCH  = (CIN >= 128) ? 2 : 1;  // chunk CIN to bound LDS
    constexpr int CINC = CIN / NCH;
    constexpr int SITER = CINC / 4 / LOADERS;

    const int k  = blockIdx.y;
    const int ct = blockIdx.z * CTILE;

    __shared__ float Wl[CIN][CTILE];
    __shared__ float ft[CINC][FTS];
    __shared__ int   sslot[PP];

    {   // stage full W[k] cout-tile
        const float* Wk = W + (size_t)k * CIN * COUT + ct;
        for (int i = threadIdx.x; i < CIN * NCG; i += 256) {
            int j = i / NCG, c4 = (i % NCG) * 4;
            *(float4*)&Wl[j][c4] = *(const float4*)(Wk + (size_t)j * COUT + c4);
        }
    }

    const int cg = threadIdx.x % NCG;
    const int pg = threadIdx.x / NCG;
    const int pl = threadIdx.x % PP;
    const int ll = threadIdx.x / PP;

    const int* iin  = in_idx  + (size_t)k * M;
    const int* iout = out_idx + (size_t)k * M;
    const int* rk   = rank    + (size_t)k * M;

    for (int base = blockIdx.x * PP; base < M; base += gridDim.x * PP) {
        float4 acc[4];
        #pragma unroll
        for (int q = 0; q < 4; ++q) { acc[q].x = acc[q].y = acc[q].z = acc[q].w = 0.f; }
        const int p0 = pg * 4;

        #pragma unroll
        for (int ch = 0; ch < NCH; ++ch) {
            __syncthreads();   // protect ft/sslot reuse
            int p = base + pl;
            if (p < M) {
                if (ch == 0 && threadIdx.x < PP)
                    sslot[pl] = ptr[iout[p]] + rk[p];
                const float* fr = feats + (size_t)iin[p] * CIN + ch * CINC;
                #pragma unroll
                for (int i = 0; i < SITER; ++i) {
                    int j4 = (ll + i * LOADERS) * 4;
                    float4 v = *(const float4*)(fr + j4);
                    ft[j4 + 0][pl] = v.x;
                    ft[j4 + 1][pl] = v.y;
                    ft[j4 + 2][pl] = v.z;
                    ft[j4 + 3][pl] = v.w;
                }
            }
            __syncthreads();

            #pragma unroll 4
            for (int j = 0; j < CINC; ++j) {
                float4 wv = *(const float4*)&Wl[ch * CINC + j][cg * 4];
                float4 fv = *(const float4*)&ft[j][p0];
                acc[0].x = fmaf(wv.x, fv.x, acc[0].x);
                acc[0].y = fmaf(wv.y, fv.x, acc[0].y);
                acc[0].z = fmaf(wv.z, fv.x, acc[0].z);
                acc[0].w = fmaf(wv.w, fv.x, acc[0].w);
                acc[1].x = fmaf(wv.x, fv.y, acc[1].x);
                acc[1].y = fmaf(wv.y, fv.y, acc[1].y);
                acc[1].z = fmaf(wv.z, fv.y, acc[1].z);
                acc[1].w = fmaf(wv.w, fv.y, acc[1].w);
                acc[2].x = fmaf(wv.x, fv.z, acc[2].x);
                acc[2].y = fmaf(wv.y, fv.z, acc[2].y);
                acc[2].z = fmaf(wv.z, fv.z, acc[2].z);
                acc[2].w = fmaf(wv.w, fv.z, acc[2].w);
                acc[3].x = fmaf(wv.x, fv.w, acc[3].x);
                acc[3].y = fmaf(wv.y, fv.w, acc[3].y);
                acc[3].z = fmaf(wv.z, fv.w, acc[3].z);
                acc[3].w = fmaf(wv.w, fv.w, acc[3].w);
            }
        }

        #pragma unroll
        for (int q = 0; q < 4; ++q) {
            int pq = base + p0 + q;
            if (pq < M) {
                int s = sslot[p0 + q];
                *(float4*)(contrib + (size_t)s * COUT + ct + cg * 4) = acc[q];
            }
        }
    }
}

// ---------------- Phase B: segmented sum over sorted contributions ----------
template <int COUT>
__global__ __launch_bounds__(256) void phaseB(
    const float* __restrict__ contrib, const int* __restrict__ ptr,
    float* __restrict__ out, int n, int accum)
{
    int total = n * COUT;
    for (int idx = blockIdx.x * 256 + threadIdx.x; idx < total; idx += gridDim.x * 256) {
        int o = idx / COUT, c = idx % COUT;
        int s0 = ptr[o];
        int s1 = ptr[o + 1];
        float acc = accum ? out[idx] : 0.f;
        for (int s = s0; s < s1; ++s) acc += contrib[(size_t)s * COUT + c];
        out[idx] = acc;
    }
}

// ---------------- elementwise ReLU ----------------
__global__ __launch_bounds__(256) void relu_kernel(float* __restrict__ x, int total)
{
    for (int i = blockIdx.x * 256 + threadIdx.x; i < total; i += gridDim.x * 256)
        x[i] = fmaxf(x[i], 0.f);
}

// ---------------- BN ----------------
template <int C>
__global__ __launch_bounds__(256) void bn_stats_kernel(
    const float* __restrict__ x, int n, float* __restrict__ sums)
{
    float s = 0.f, s2 = 0.f;
    size_t total = (size_t)n * C;
    size_t stride = (size_t)gridDim.x * 256;
    for (size_t i = (size_t)blockIdx.x * 256 + threadIdx.x; i < total; i += stride) {
        float v = x[i];
        s += v; s2 += v * v;
    }
    __shared__ float ls[256], ls2[256];
    ls[threadIdx.x] = s; ls2[threadIdx.x] = s2;
    __syncthreads();
    for (int off = 128; off >= C; off >>= 1) {
        if (threadIdx.x < (unsigned)off) {
            ls[threadIdx.x]  += ls[threadIdx.x + off];
            ls2[threadIdx.x] += ls2[threadIdx.x + off];
        }
        __syncthreads();
    }
    if (threadIdx.x < C) {
        atomicAdd(&sums[threadIdx.x], ls[threadIdx.x]);
        atomicAdd(&sums[C + threadIdx.x], ls2[threadIdx.x]);
    }
}

template <int C>
__global__ __launch_bounds__(256) void bn_apply_relu_kernel(
    float* __restrict__ x, int n, const float* __restrict__ sums,
    const float* __restrict__ g, const float* __restrict__ b)
{
    const int c = threadIdx.x % C;
    const float inv_n = 1.0f / (float)n;
    float mean = sums[c] * inv_n;
    float var  = sums[C + c] * inv_n - mean * mean;
    float scale = g[c] * rsqrtf(var + EPSc);
    float shift = b[c] - mean * scale;
    size_t total = (size_t)n * C;
    size_t stride = (size_t)gridDim.x * 256;
    for (size_t i = (size_t)blockIdx.x * 256 + threadIdx.x; i < total; i += stride)
        x[i] = fmaxf(x[i] * scale + shift, 0.f);
}

// ---------------- host-side per-layer driver ----------------
struct CsrBufs {
    int* bins;   // n_out+1 (zeroed per chunk)
    int* ptr;    // n_out+1
    int* bsums;  // >= 98
};

static inline void build_csr(const int* iout_chunk, int* rank, int Ec,
                             const CsrBufs& cb, int n_out, hipStream_t s)
{
    hipMemsetAsync(cb.bins, 0, (size_t)(n_out + 1) * sizeof(int), s);
    int gb = std::min(2048, (Ec + 255) / 256);
    hipLaunchKernelGGL(rank_kernel, dim3(gb), dim3(256), 0, s, iout_chunk, rank, cb.bins, Ec);
    int nb = (n_out + 1 + 1023) / 1024;
    hipLaunchKernelGGL(scan1, dim3(nb), dim3(256), 0, s, cb.bins, cb.ptr, cb.bsums, n_out + 1);
    hipLaunchKernelGGL(scan2, dim3(1), dim3(256), 0, s, cb.bsums, nb);
    hipLaunchKernelGGL(scan3, dim3(nb), dim3(256), 0, s, cb.ptr, cb.bsums, n_out + 1);
}

template <int CIN, int COUT, int CTILE>
static void run_layer(const float* feats, const float* W,
                      const int* iin, const int* iout, float* outp,
                      int M, int K, int n_out, const CsrBufs& cb,
                      int* region, long long cap_elems, hipStream_t s)
{
    constexpr int PP = 4096 / CTILE;
    const long long per_k = (long long)M * (COUT + 1);
    int q = (int)std::min<long long>((long long)K, (cap_elems - 8) / per_k);
    if (q < 1) q = 1;
    bool first = true;
    for (int k0 = 0; k0 < K; k0 += q) {
        int qc = std::min(q, K - k0);
        int Ec = qc * M;
        int* rank = region;
        float* contrib = (float*)(region + ((Ec + 3) & ~3));
        build_csr(iout + (size_t)k0 * M, rank, Ec, cb, n_out, s);
        dim3 g((M + PP - 1) / PP, qc, COUT / CTILE);
        hipLaunchKernelGGL((phaseA_tiled<CIN, COUT, CTILE>), g, dim3(256), 0, s,
                           feats, W + (size_t)k0 * CIN * COUT,
                           iin + (size_t)k0 * M, iout + (size_t)k0 * M,
                           cb.ptr, rank, contrib, M);
        hipLaunchKernelGGL((phaseB<COUT>), dim3(2048), dim3(256), 0, s,
                           contrib, cb.ptr, outp, n_out, first ? 0 : 1);
        first = false;
    }
}

static void run_layer_1a(const float* x, const float* W,
                         const int* iin, const int* iout, float* outp,
                         int M, int K, int n_out, const CsrBufs& cb,
                         int* region, long long cap_elems, hipStream_t s)
{
    const long long per_k = (long long)M * 33;
    int q = (int)std::min<long long>((long long)K, (cap_elems - 8) / per_k);
    if (q < 1) q = 1;
    bool first = true;
    for (int k0 = 0; k0 < K; k0 += q) {
        int qc = std::min(q, K - k0);
        int Ec = qc * M;
        int* rank = region;
        float* contrib = (float*)(region + ((Ec + 3) & ~3));
        build_csr(iout + (size_t)k0 * M, rank, Ec, cb, n_out, s);
        dim3 g((M + 127) / 128, qc, 1);
        hipLaunchKernelGGL(phaseA_1a, g, dim3(256), 0, s,
                           x, W + (size_t)k0 * 32,
                           iin + (size_t)k0 * M, iout + (size_t)k0 * M,
                           cb.ptr, rank, contrib, M);
        hipLaunchKernelGGL((phaseB<32>), dim3(2048), dim3(256), 0, s,
                           contrib, cb.ptr, outp, n_out, first ? 0 : 1);
        first = false;
    }
}

template <int C>
static void launch_bn(float* x, int n, float* sums,
                      const float* g, const float* b, hipStream_t s)
{
    hipLaunchKernelGGL((bn_stats_kernel<C>), dim3(512), dim3(256), 0, s, x, n, sums);
    hipLaunchKernelGGL((bn_apply_relu_kernel<C>), dim3(2048), dim3(256), 0, s, x, n, sums, g, b);
}

extern "C" void kernel_launch(void* const* d_in, const int* in_sizes, int n_in,
                              void* d_out, int out_size, void* d_ws, size_t ws_size,
                              hipStream_t stream)
{
    const float* x_feats = (const float*)d_in[0];
    const float* w1a = (const float*)d_in[1];
    const float* w1b = (const float*)d_in[2];
    const float* w1c = (const float*)d_in[3];
    const float* w2  = (const float*)d_in[4];
    const float* w3a = (const float*)d_in[5];
    const float* w3b = (const float*)d_in[6];
    const float* bn1b_g = (const float*)d_in[7];
    const float* bn1b_b = (const float*)d_in[8];
    const float* bn1c_g = (const float*)d_in[9];
    const float* bn1c_b = (const float*)d_in[10];
    const float* bn3a_g = (const float*)d_in[11];
    const float* bn3a_b = (const float*)d_in[12];
    const float* bn3b_g = (const float*)d_in[13];
    const float* bn3b_b = (const float*)d_in[14];
    const int* km1a_in  = (const int*)d_in[15];
    const int* km1a_out = (const int*)d_in[16];
    const int* km1b_in  = (const int*)d_in[17];
    const int* km1b_out = (const int*)d_in[18];
    const int* km1c_in  = (const int*)d_in[19];
    const int* km1c_out = (const int*)d_in[20];
    const int* km2_in   = (const int*)d_in[21];
    const int* km2_out  = (const int*)d_in[22];
    const int* km3a_in  = (const int*)d_in[23];
    const int* km3a_out = (const int*)d_in[24];
    const int* km3b_in  = (const int*)d_in[25];
    const int* km3b_out = (const int*)d_in[26];

    float* out  = (float*)d_out;
    float* x_e1 = out;                       // [N1,32]
    float* x_e2 = out + (size_t)N1c * 32;    // [N2,256] -- also scratch until conv3b

    // ---- fixed workspace layout (element offsets; 16B-aligned) ----
    float* ws = (float*)d_ws;
    float* poolA = ws;                               // 10,240,000 f (h1 -> h3)
    float* poolB = poolA + 10240000;                 //  5,120,000 f (h2 -> h2b)
    float* stats = poolB + 5120000;                  //      2,048 f
    int*   bins  = (int*)(stats + 2048);             //    100,016 i
    int*   ptr   = bins + 100016;                    //    100,016 i
    int*   bsums = ptr + 100016;                     //        512 i
    int*   dynbuf = bsums + 512;                     // rest: rank|contrib
    const long long FIXED = 10240000LL + 5120000 + 2048 + 100016 + 100016 + 512;
    long long dyn_elems = (long long)(ws_size / 4) - FIXED;
    if (dyn_elems < 0) dyn_elems = 0;

    float* h1  = poolA;   // [N1,32]
    float* h3  = poolA;   // [N2,128] (h1 dead by then)
    float* h2  = poolB;   // [N1,32]
    float* h2b = poolB;   // [N2,64] (h2 dead by then)

    CsrBufs cb{bins, ptr, bsums};
    float* st1b = stats;
    float* st1c = stats + 512;
    float* st3a = stats + 1024;
    float* st3b = stats + 1536;
    hipMemsetAsync(stats, 0, 2048 * sizeof(float), stream);

    // x_e2 region of d_out is free scratch until the last layer
    const long long alt_elems = (long long)N2c * 256;    // 20,480,000
    int* altbuf = (int*)x_e2;
    const bool use_alt = alt_elems > dyn_elems;  // pick the larger region for pre-3b layers
    int*      early_region = use_alt ? altbuf : dynbuf;
    long long early_cap    = use_alt ? alt_elems : dyn_elems;

    // ---- enc1: conv1a (1->32, K=125) + ReLU ----
    run_layer_1a(x_feats, w1a, km1a_in, km1a_out, h1, 20000, 125, N1c,
                 cb, early_region, early_cap, stream);
    hipLaunchKernelGGL(relu_kernel, dim3(2048), dim3(256), 0, stream, h1, N1c * 32);

    // ---- conv1b (32->32, K=125) + BN + ReLU ----
    run_layer<32, 32, 32>(h1, w1b, km1b_in, km1b_out, h2, 20000, 125, N1c,
                          cb, early_region, early_cap, stream);
    launch_bn<32>(h2, N1c, st1b, bn1b_g, bn1b_b, stream);

    // ---- conv1c (32->32, K=125) + BN + ReLU -> x_e1 ----
    run_layer<32, 32, 32>(h2, w1c, km1c_in, km1c_out, x_e1, 20000, 125, N1c,
                          cb, early_region, early_cap, stream);
    launch_bn<32>(x_e1, N1c, st1c, bn1c_g, bn1c_b, stream);

    // ---- conv2 (32->64, K=27), no activation ----
    run_layer<32, 64, 64>(x_e1, w2, km2_in, km2_out, h2b, 30000, 27, N2c,
                          cb, early_region, early_cap, stream);

    // ---- conv3a (64->128, K=27) + BN + ReLU ----
    run_layer<64, 128, 128>(h2b, w3a, km3a_in, km3a_out, h3, 20000, 27, N2c,
                            cb, early_region, early_cap, stream);
    launch_bn<128>(h3, N2c, st3a, bn3a_g, bn3a_b, stream);

    // ---- conv3b (128->256, K=27) + BN + ReLU -> x_e2 (ws region only!) ----
    run_layer<128, 256, 64>(h3, w3b, km3b_in, km3b_out, x_e2, 20000, 27, N2c,
                            cb, dynbuf, dyn_elems, stream);
    launch_bn<256>(x_e2, N2c, st3b, bn3b_g, bn3b_b, stream);
}

// Round 4
// 2743.158 us; speedup vs baseline: 1.5219x; 1.0225x over previous
//
#include <hip/hip_runtime.h>
#include <cstdint>
#include <algorithm>

// ---------------- problem constants ----------------
#define N1c 100000
#define N2c 80000
#define EPSc 1e-5f
#define STRIDE_N1 102400   // 100 blocks of 1024 (>= N1+1 bins, padded)
#define STRIDE_N2 81920    // 80 blocks of 1024  (>= N2+1 bins, padded)

// ---------------- CSR build: one pass for ALL k-chunks of a layer ----------
__global__ __launch_bounds__(256) void rank2d_kernel(
    const int* __restrict__ out_idx, int* __restrict__ rank,
    int* __restrict__ bins, int E, int M, int q, int stride)
{
    for (int e = blockIdx.x * 256 + threadIdx.x; e < E; e += gridDim.x * 256) {
        int chunk = (e / M) / q;
        rank[e] = atomicAdd(&bins[chunk * stride + out_idx[e]], 1);
    }
}

__global__ __launch_bounds__(256) void scan1(
    const int* __restrict__ bins, int* __restrict__ ptr,
    int* __restrict__ bsums, int n)
{
    __shared__ int lds[256];
    int base = blockIdx.x * 1024;
    int v[4]; int t = 0;
    #pragma unroll
    for (int i = 0; i < 4; ++i) {
        int idx = base + threadIdx.x * 4 + i;
        v[i] = idx < n ? bins[idx] : 0;
        t += v[i];
    }
    lds[threadIdx.x] = t; __syncthreads();
    for (int off = 1; off < 256; off <<= 1) {
        int x = threadIdx.x >= off ? lds[threadIdx.x - off] : 0;
        __syncthreads();
        lds[threadIdx.x] += x;
        __syncthreads();
    }
    int run = lds[threadIdx.x] - t;
    if (threadIdx.x == 255) bsums[blockIdx.x] = lds[255];
    #pragma unroll
    for (int i = 0; i < 4; ++i) {
        int idx = base + threadIdx.x * 4 + i;
        if (idx < n) ptr[idx] = run;
        run += v[i];
    }
}

// serial exclusive scan of block sums, carry reset at chunk boundaries
__global__ __launch_bounds__(64) void scan2s(
    int* __restrict__ bsums, int bpc, int nch)
{
    int c = threadIdx.x;
    if (c < nch) {
        int run = 0;
        for (int i = 0; i < bpc; ++i) {
            int idx = c * bpc + i;
            int t = bsums[idx]; bsums[idx] = run; run += t;
        }
    }
}

__global__ __launch_bounds__(256) void scan3(
    int* __restrict__ ptr, const int* __restrict__ bsums, int n)
{
    int idx = blockIdx.x * 1024 + threadIdx.x * 4;
    int add = bsums[blockIdx.x];
    #pragma unroll
    for (int i = 0; i < 4; ++i)
        if (idx + i < n) ptr[idx + i] += add;
}

// ---------------- conv1a special: scatter (x_val, k) 8B per edge ----------
__global__ __launch_bounds__(256) void scatter_1a(
    const float* __restrict__ x, const int* __restrict__ iin,
    const int* __restrict__ iout, const int* __restrict__ ptr,
    const int* __restrict__ rank, float2* __restrict__ payload, int E, int M)
{
    for (int e = blockIdx.x * 256 + threadIdx.x; e < E; e += gridDim.x * 256) {
        int k = e / M;
        float2 p; p.x = x[iin[e]]; p.y = __int_as_float(k);
        payload[ptr[iout[e]] + rank[e]] = p;
    }
}

// out[o][c] = relu( sum_e val_e * W[k_e][c] ), W (125x32) in LDS
__global__ __launch_bounds__(256) void phaseB_1a(
    const float2* __restrict__ payload, const int* __restrict__ ptr,
    const float* __restrict__ W, float* __restrict__ out, int n)
{
    __shared__ float Wl[125 * 32];
    for (int i = threadIdx.x; i < 125 * 32; i += 256) Wl[i] = W[i];
    __syncthreads();
    int total = n * 32;
    for (int idx = blockIdx.x * 256 + threadIdx.x; idx < total; idx += gridDim.x * 256) {
        int o = idx >> 5, c = idx & 31;
        int s0 = ptr[o], s1 = ptr[o + 1];
        float acc = 0.f;
        for (int s = s0; s < s1; ++s) {
            float2 p = payload[s];
            acc = fmaf(p.x, Wl[(__float_as_int(p.y) << 5) + c], acc);
        }
        out[idx] = fmaxf(acc, 0.f);
    }
}

// ---------------- Phase A: tiled gather-GEMM, sorted plain-store scatter ----
// GMODE: 0 = plain gather, 2 = BN(scale/shift)+ReLU at gather
template <int CIN, int COUT, int CTILE, int GMODE>
__global__ __launch_bounds__(256) void phaseA_tiled(
    const float* __restrict__ feats, const float* __restrict__ W, // [qc,CIN,COUT]
    const int* __restrict__ in_idx, const int* __restrict__ out_idx,
    const int* __restrict__ ptr, const int* __restrict__ rank,
    float* __restrict__ contrib, int M,
    const float* __restrict__ sc, const float* __restrict__ sh)
{
    constexpr int PP   = 4096 / CTILE;
    constexpr int NCG  = CTILE / 4;
    constexpr int LOADERS = 256 / PP;
    constexpr int FTS  = PP + 4;
    constexpr int NCH  = (CIN >= 128) ? 2 : 1;
    constexpr int CINC = CIN / NCH;
    constexpr int SITER = CINC / 4 / LOADERS;

    const int k  = blockIdx.y;
    const int ct = blockIdx.z * CTILE;

    __shared__ float Wl[CIN][CTILE];
    __shared__ float ft[CINC][FTS];
    __shared__ int   sslot[PP];

    {
        const float* Wk = W + (size_t)k * CIN * COUT + ct;
        for (int i = threadIdx.x; i < CIN * NCG; i += 256) {
            int j = i / NCG, c4 = (i % NCG) * 4;
            *(float4*)&Wl[j][c4] = *(const float4*)(Wk + (size_t)j * COUT + c4);
        }
    }

    const int cg = threadIdx.x % NCG;
    const int pg = threadIdx.x / NCG;
    const int pl = threadIdx.x % PP;
    const int ll = threadIdx.x / PP;

    const int* iin  = in_idx  + (size_t)k * M;
    const int* iout = out_idx + (size_t)k * M;
    const int* rk   = rank    + (size_t)k * M;

    for (int base = blockIdx.x * PP; base < M; base += gridDim.x * PP) {
        float4 acc[4];
        #pragma unroll
        for (int q = 0; q < 4; ++q) { acc[q].x = acc[q].y = acc[q].z = acc[q].w = 0.f; }
        const int p0 = pg * 4;

        #pragma unroll
        for (int ch = 0; ch < NCH; ++ch) {
            __syncthreads();
            int p = base + pl;
            if (p < M) {
                if (ch == 0 && threadIdx.x < PP)
                    sslot[pl] = ptr[iout[p]] + rk[p];
                const float* fr = feats + (size_t)iin[p] * CIN + ch * CINC;
                #pragma unroll
                for (int i = 0; i < SITER; ++i) {
                    int j4 = (ll + i * LOADERS) * 4;
                    float4 v = *(const float4*)(fr + j4);
                    if (GMODE == 2) {
                        float4 s4 = *(const float4*)(sc + ch * CINC + j4);
                        float4 h4 = *(const float4*)(sh + ch * CINC + j4);
                        v.x = fmaxf(fmaf(v.x, s4.x, h4.x), 0.f);
                        v.y = fmaxf(fmaf(v.y, s4.y, h4.y), 0.f);
                        v.z = fmaxf(fmaf(v.z, s4.z, h4.z), 0.f);
                        v.w = fmaxf(fmaf(v.w, s4.w, h4.w), 0.f);
                    }
                    ft[j4 + 0][pl] = v.x;
                    ft[j4 + 1][pl] = v.y;
                    ft[j4 + 2][pl] = v.z;
                    ft[j4 + 3][pl] = v.w;
                }
            }
            __syncthreads();

            #pragma unroll 4
            for (int j = 0; j < CINC; ++j) {
                float4 wv = *(const float4*)&Wl[ch * CINC + j][cg * 4];
                float4 fv = *(const float4*)&ft[j][p0];
                acc[0].x = fmaf(wv.x, fv.x, acc[0].x);
                acc[0].y = fmaf(wv.y, fv.x, acc[0].y);
                acc[0].z = fmaf(wv.z, fv.x, acc[0].z);
                acc[0].w = fmaf(wv.w, fv.x, acc[0].w);
                acc[1].x = fmaf(wv.x, fv.y, acc[1].x);
                acc[1].y = fmaf(wv.y, fv.y, acc[1].y);
                acc[1].z = fmaf(wv.z, fv.y, acc[1].z);
                acc[1].w = fmaf(wv.w, fv.y, acc[1].w);
                acc[2].x = fmaf(wv.x, fv.z, acc[2].x);
                acc[2].y = fmaf(wv.y, fv.z, acc[2].y);
                acc[2].z = fmaf(wv.z, fv.z, acc[2].z);
                acc[2].w = fmaf(wv.w, fv.z, acc[2].w);
                acc[3].x = fmaf(wv.x, fv.w, acc[3].x);
                acc[3].y = fmaf(wv.y, fv.w, acc[3].y);
                acc[3].z = fmaf(wv.z, fv.w, acc[3].z);
                acc[3].w = fmaf(wv.w, fv.w, acc[3].w);
            }
        }

        #pragma unroll
        for (int q = 0; q < 4; ++q) {
            int pq = base + p0 + q;
            if (pq < M) {
                int s = sslot[p0 + q];
                *(float4*)(contrib + (size_t)s * COUT + ct + cg * 4) = acc[q];
            }
        }
    }
}

// ---------------- Phase B: segmented sum (+optional fused BN stats) --------
template <int COUT, bool STATS>
__global__ __launch_bounds__(256) void phaseB(
    const float* __restrict__ contrib, const int* __restrict__ ptr,
    float* __restrict__ out, int n, int accum, float* __restrict__ statsbuf)
{
    float s1 = 0.f, s2 = 0.f;
    int total = n * COUT;
    for (int idx = blockIdx.x * 256 + threadIdx.x; idx < total; idx += gridDim.x * 256) {
        int o = idx / COUT, c = idx % COUT;
        int a = ptr[o], b = ptr[o + 1];
        float acc = accum ? out[idx] : 0.f;
        for (int s = a; s < b; ++s) acc += contrib[(size_t)s * COUT + c];
        out[idx] = acc;
        if (STATS) { s1 += acc; s2 += acc * acc; }
    }
    if constexpr (STATS) {
        __shared__ float l1[256], l2[256];
        l1[threadIdx.x] = s1; l2[threadIdx.x] = s2;
        __syncthreads();
        for (int off = 128; off >= COUT; off >>= 1) {
            if (threadIdx.x < (unsigned)off) {
                l1[threadIdx.x] += l1[threadIdx.x + off];
                l2[threadIdx.x] += l2[threadIdx.x + off];
            }
            __syncthreads();
        }
        if (threadIdx.x < COUT) {
            atomicAdd(&statsbuf[threadIdx.x], l1[threadIdx.x]);
            atomicAdd(&statsbuf[COUT + threadIdx.x], l2[threadIdx.x]);
        }
    }
}

// ---------------- BN helpers ----------------
template <int C>
__global__ __launch_bounds__(256) void make_scsh(
    const float* __restrict__ sums, const float* __restrict__ g,
    const float* __restrict__ b, float* __restrict__ sc, float* __restrict__ sh,
    float inv_n)
{
    int c = threadIdx.x;
    if (c < C) {
        float mean = sums[c] * inv_n;
        float var  = sums[C + c] * inv_n - mean * mean;
        float s = g[c] * rsqrtf(var + EPSc);
        sc[c] = s;
        sh[c] = b[c] - mean * s;
    }
}

template <int C>
__global__ __launch_bounds__(256) void bn_apply_relu_kernel(
    float* __restrict__ x, int n, const float* __restrict__ sums,
    const float* __restrict__ g, const float* __restrict__ b)
{
    const int c = threadIdx.x % C;
    const float inv_n = 1.0f / (float)n;
    float mean = sums[c] * inv_n;
    float var  = sums[C + c] * inv_n - mean * mean;
    float scale = g[c] * rsqrtf(var + EPSc);
    float shift = b[c] - mean * scale;
    size_t total = (size_t)n * C;
    size_t stride = (size_t)gridDim.x * 256;
    for (size_t i = (size_t)blockIdx.x * 256 + threadIdx.x; i < total; i += stride)
        x[i] = fmaxf(x[i] * scale + shift, 0.f);
}

// ---------------- host-side layer driver ----------------
struct Plan { int q, nch; };

static Plan make_plan(long long dyn_elems, int K, int M, int COUT, int stride)
{
    const long long perk = (long long)M * COUT;
    long long cap = std::min(dyn_elems - 16, 27500000LL);  // ~110 MB: L3-resident
    long long q = cap / perk;
    if (q < 1) q = 1;
    if (q > K) q = K;
    int maxch = 819200 / stride;   // bins2D capacity
    int nch = (K + (int)q - 1) / (int)q;
    if (nch > maxch) { q = (K + maxch - 1) / maxch; nch = (K + (int)q - 1) / (int)q; }
    return { (int)q, nch };
}

static void build_csr2d(const int* iout, int* rank, int* bins, int* ptr, int* bsums,
                        int E, int M, int q, int nch, int stride, hipStream_t s)
{
    hipMemsetAsync(bins, 0, (size_t)nch * stride * sizeof(int), s);
    int gb = std::min(2048, (E + 255) / 256);
    hipLaunchKernelGGL(rank2d_kernel, dim3(gb), dim3(256), 0, s, iout, rank, bins, E, M, q, stride);
    int totalbins = nch * stride, nb = totalbins / 1024, bpc = stride / 1024;
    hipLaunchKernelGGL(scan1, dim3(nb), dim3(256), 0, s, bins, ptr, bsums, totalbins);
    hipLaunchKernelGGL(scan2s, dim3(1), dim3(64), 0, s, bsums, bpc, nch);
    hipLaunchKernelGGL(scan3, dim3(nb), dim3(256), 0, s, ptr, bsums, totalbins);
}

template <int CIN, int COUT, int CTILE, int GMODE, bool STATS>
static void run_layer(const float* feats, const float* W,
                      const int* iin, const int* iout, float* outp,
                      int M, int K, int n_out, int stride,
                      int* bins, int* ptr, int* bsums, int* rank, float* contrib,
                      long long dyn_elems, const float* sc, const float* sh,
                      float* statsbuf, hipStream_t s)
{
    constexpr int PP = 4096 / CTILE;
    Plan pl = make_plan(dyn_elems, K, M, COUT, stride);
    build_csr2d(iout, rank, bins, ptr, bsums, K * M, M, pl.q, pl.nch, stride, s);
    for (int ch = 0; ch < pl.nch; ++ch) {
        int k0 = ch * pl.q;
        int qc = std::min(pl.q, K - k0);
        dim3 g((M + PP - 1) / PP, qc, COUT / CTILE);
        hipLaunchKernelGGL((phaseA_tiled<CIN, COUT, CTILE, GMODE>), g, dim3(256), 0, s,
                           feats, W + (size_t)k0 * CIN * COUT,
                           iin + (size_t)k0 * M, iout + (size_t)k0 * M,
                           ptr + (size_t)ch * stride, rank + (size_t)k0 * M,
                           contrib, M, sc, sh);
        bool last = (ch == pl.nch - 1);
        if (STATS && last)
            hipLaunchKernelGGL((phaseB<COUT, true>), dim3(2048), dim3(256), 0, s,
                               contrib, ptr + (size_t)ch * stride, outp, n_out, ch ? 1 : 0, statsbuf);
        else
            hipLaunchKernelGGL((phaseB<COUT, false>), dim3(2048), dim3(256), 0, s,
                               contrib, ptr + (size_t)ch * stride, outp, n_out, ch ? 1 : 0, (float*)nullptr);
    }
}

extern "C" void kernel_launch(void* const* d_in, const int* in_sizes, int n_in,
                              void* d_out, int out_size, void* d_ws, size_t ws_size,
                              hipStream_t stream)
{
    const float* x_feats = (const float*)d_in[0];
    const float* w1a = (const float*)d_in[1];
    const float* w1b = (const float*)d_in[2];
    const float* w1c = (const float*)d_in[3];
    const float* w2  = (const float*)d_in[4];
    const float* w3a = (const float*)d_in[5];
    const float* w3b = (const float*)d_in[6];
    const float* bn1b_g = (const float*)d_in[7];
    const float* bn1b_b = (const float*)d_in[8];
    const float* bn1c_g = (const float*)d_in[9];
    const float* bn1c_b = (const float*)d_in[10];
    const float* bn3a_g = (const float*)d_in[11];
    const float* bn3a_b = (const float*)d_in[12];
    const float* bn3b_g = (const float*)d_in[13];
    const float* bn3b_b = (const float*)d_in[14];
    const int* km1a_in  = (const int*)d_in[15];
    const int* km1a_out = (const int*)d_in[16];
    const int* km1b_in  = (const int*)d_in[17];
    const int* km1b_out = (const int*)d_in[18];
    const int* km1c_in  = (const int*)d_in[19];
    const int* km1c_out = (const int*)d_in[20];
    const int* km2_in   = (const int*)d_in[21];
    const int* km2_out  = (const int*)d_in[22];
    const int* km3a_in  = (const int*)d_in[23];
    const int* km3a_out = (const int*)d_in[24];
    const int* km3b_in  = (const int*)d_in[25];
    const int* km3b_out = (const int*)d_in[26];

    float* out  = (float*)d_out;
    float* x_e1 = out;                       // [N1,32]
    float* x_e2 = out + (size_t)N1c * 32;    // [N2,256]

    // ---- workspace layout (element offsets) ----
    float* ws = (float*)d_ws;
    float* poolA = ws;                        // 10,240,000 (h1 -> h3)
    float* poolB = poolA + 10240000;          //  5,120,000 (h2 -> h2b)
    float* stats = poolB + 5120000;           //      2,048 (4 x 512)
    float* scsh  = stats + 2048;              //      1,024
    int*   bins  = (int*)(scsh + 1024);       //    819,200
    int*   ptr   = bins + 819200;             //    819,200
    int*   bsums = ptr + 819200;              //      1,024
    int*   rank  = bsums + 1024;              //  2,500,000
    float* contrib = (float*)(rank + 2500000);
    const long long FIXED = 10240000LL + 5120000 + 2048 + 1024 + 819200 + 819200 + 1024 + 2500000;
    long long dyn_elems = (long long)(ws_size / 4) - FIXED;
    if (dyn_elems < 0) dyn_elems = 0;

    float* h1  = poolA;   // [N1,32]
    float* h3  = poolA;   // [N2,128] (h1 dead by then)
    float* h2  = poolB;   // [N1,32]
    float* h2b = poolB;   // [N2,64]  (h2 dead by then)

    float* st1b = stats;
    float* st1c = stats + 512;
    float* st3a = stats + 1024;
    float* st3b = stats + 1536;
    float* sc1b = scsh,       *sh1b = scsh + 32;
    float* sc3a = scsh + 256, *sh3a = scsh + 384;

    hipMemsetAsync(stats, 0, 2048 * sizeof(float), stream);

    // ---- conv1a (1->32, K=125) + ReLU: scatter (val,k) + W-in-LDS reduce ----
    {
        build_csr2d(km1a_out, rank, bins, ptr, bsums, 125 * 20000, 20000, 125, 1, STRIDE_N1, stream);
        hipLaunchKernelGGL(scatter_1a, dim3(2048), dim3(256), 0, stream,
                           x_feats, km1a_in, km1a_out, ptr, rank, (float2*)contrib,
                           125 * 20000, 20000);
        hipLaunchKernelGGL(phaseB_1a, dim3(2048), dim3(256), 0, stream,
                           (const float2*)contrib, ptr, w1a, h1, N1c);
    }

    // ---- conv1b (32->32, K=125): raw out + fused stats; BN applied at next gather
    run_layer<32, 32, 32, 0, true>(h1, w1b, km1b_in, km1b_out, h2, 20000, 125, N1c,
                                   STRIDE_N1, bins, ptr, bsums, rank, contrib, dyn_elems,
                                   nullptr, nullptr, st1b, stream);
    hipLaunchKernelGGL((make_scsh<32>), dim3(1), dim3(256), 0, stream,
                       st1b, bn1b_g, bn1b_b, sc1b, sh1b, 1.0f / N1c);

    // ---- conv1c (32->32, K=125): BN(h2)+ReLU fused at gather; out x_e1 raw + stats
    run_layer<32, 32, 32, 2, true>(h2, w1c, km1c_in, km1c_out, x_e1, 20000, 125, N1c,
                                   STRIDE_N1, bins, ptr, bsums, rank, contrib, dyn_elems,
                                   sc1b, sh1b, st1c, stream);
    hipLaunchKernelGGL((bn_apply_relu_kernel<32>), dim3(2048), dim3(256), 0, stream,
                       x_e1, N1c, st1c, bn1c_g, bn1c_b);

    // ---- conv2 (32->64, K=27): plain, no activation ----
    run_layer<32, 64, 64, 0, false>(x_e1, w2, km2_in, km2_out, h2b, 30000, 27, N2c,
                                    STRIDE_N2, bins, ptr, bsums, rank, contrib, dyn_elems,
                                    nullptr, nullptr, nullptr, stream);

    // ---- conv3a (64->128, K=27): raw out + stats; BN applied at conv3b gather
    run_layer<64, 128, 128, 0, true>(h2b, w3a, km3a_in, km3a_out, h3, 20000, 27, N2c,
                                     STRIDE_N2, bins, ptr, bsums, rank, contrib, dyn_elems,
                                     nullptr, nullptr, st3a, stream);
    hipLaunchKernelGGL((make_scsh<128>), dim3(1), dim3(256), 0, stream,
                       st3a, bn3a_g, bn3a_b, sc3a, sh3a, 1.0f / N2c);

    // ---- conv3b (128->256, K=27): BN(h3)+ReLU at gather; out x_e2 + stats + BN apply
    run_layer<128, 256, 64, 2, true>(h3, w3b, km3b_in, km3b_out, x_e2, 20000, 27, N2c,
                                     STRIDE_N2, bins, ptr, bsums, rank, contrib, dyn_elems,
                                     sc3a, sh3a, st3b, stream);
    hipLaunchKernelGGL((bn_apply_relu_kernel<256>), dim3(2048), dim3(256), 0, stream,
                       x_e2, N2c, st3b, bn3b_g, bn3b_b);
}

// Round 5
// 2491.765 us; speedup vs baseline: 1.6755x; 1.1009x over previous
//
#include <hip/hip_runtime.h>
#include <cstdint>
#include <algorithm>

// ---------------- problem constants ----------------
#define N1c 100000
#define N2c 80000
#define EPSc 1e-5f
#define STRIDE_N1 102400   // 100 blocks of 1024 (>= N1+1 bins)
#define STRIDE_N2 81920    // 80 blocks of 1024  (>= N2+1 bins)

// ---------------- CSR build: one pass for ALL k-chunks of a layer ----------
__global__ __launch_bounds__(256) void rank2d_kernel(
    const int* __restrict__ out_idx, int* __restrict__ rank,
    int* __restrict__ bins, int E, int M, int q, int stride)
{
    for (int e = blockIdx.x * 256 + threadIdx.x; e < E; e += gridDim.x * 256) {
        int chunk = (e / M) / q;
        rank[e] = atomicAdd(&bins[chunk * stride + out_idx[e]], 1);
    }
}

__global__ __launch_bounds__(256) void scan1(
    const int* __restrict__ bins, int* __restrict__ ptr,
    int* __restrict__ bsums, int n)
{
    __shared__ int lds[256];
    int base = blockIdx.x * 1024;
    int v[4]; int t = 0;
    #pragma unroll
    for (int i = 0; i < 4; ++i) {
        int idx = base + threadIdx.x * 4 + i;
        v[i] = idx < n ? bins[idx] : 0;
        t += v[i];
    }
    lds[threadIdx.x] = t; __syncthreads();
    for (int off = 1; off < 256; off <<= 1) {
        int x = threadIdx.x >= off ? lds[threadIdx.x - off] : 0;
        __syncthreads();
        lds[threadIdx.x] += x;
        __syncthreads();
    }
    int run = lds[threadIdx.x] - t;
    if (threadIdx.x == 255) bsums[blockIdx.x] = lds[255];
    #pragma unroll
    for (int i = 0; i < 4; ++i) {
        int idx = base + threadIdx.x * 4 + i;
        if (idx < n) ptr[idx] = run;
        run += v[i];
    }
}

// serial exclusive scan of block sums, carry reset at chunk boundaries
__global__ __launch_bounds__(64) void scan2s(
    int* __restrict__ bsums, int bpc, int nch)
{
    int c = threadIdx.x;
    if (c < nch) {
        int run = 0;
        for (int i = 0; i < bpc; ++i) {
            int idx = c * bpc + i;
            int t = bsums[idx]; bsums[idx] = run; run += t;
        }
    }
}

__global__ __launch_bounds__(256) void scan3(
    int* __restrict__ ptr, const int* __restrict__ bsums, int n)
{
    int idx = blockIdx.x * 1024 + threadIdx.x * 4;
    int add = bsums[blockIdx.x];
    #pragma unroll
    for (int i = 0; i < 4; ++i)
        if (idx + i < n) ptr[idx + i] += add;
}

// ---------------- conv1a special: scatter (x_val, k) 8B per edge ----------
__global__ __launch_bounds__(256) void scatter_1a(
    const float* __restrict__ x, const int* __restrict__ iin,
    const int* __restrict__ iout, const int* __restrict__ ptr,
    const int* __restrict__ rank, float2* __restrict__ payload, int E, int M)
{
    for (int e = blockIdx.x * 256 + threadIdx.x; e < E; e += gridDim.x * 256) {
        int k = e / M;
        float2 p; p.x = x[iin[e]]; p.y = __int_as_float(k);
        payload[ptr[iout[e]] + rank[e]] = p;
    }
}

// out[o][c] = relu( sum_e val_e * W[k_e][c] ), W (125x32) in LDS
__global__ __launch_bounds__(256) void phaseB_1a(
    const float2* __restrict__ payload, const int* __restrict__ ptr,
    const float* __restrict__ W, float* __restrict__ out, int n)
{
    __shared__ float Wl[125 * 32];
    for (int i = threadIdx.x; i < 125 * 32; i += 256) Wl[i] = W[i];
    __syncthreads();
    int total = n * 32;
    for (int idx = blockIdx.x * 256 + threadIdx.x; idx < total; idx += gridDim.x * 256) {
        int o = idx >> 5, c = idx & 31;
        int s0 = ptr[o], s1 = ptr[o + 1];
        float acc = 0.f;
        for (int s = s0; s < s1; ++s) {
            float2 p = payload[s];
            acc = fmaf(p.x, Wl[(__float_as_int(p.y) << 5) + c], acc);
        }
        out[idx] = fmaxf(acc, 0.f);
    }
}

// ---------------- Phase A: tiled gather-GEMM, 8xTC register tiles ---------
// Thread tile = TP pairs x TC couts. W row stride WST (>=CTILE for cout-split).
// GMODE: 0 = plain gather, 2 = BN(scale/shift)+ReLU at gather.
template <int CIN, int CTILE, int WST, int TP, int TC, int GMODE>
__global__ __launch_bounds__(256) void phaseA8(
    const float* __restrict__ feats, const float* __restrict__ W,
    const int* __restrict__ in_idx, const int* __restrict__ out_idx,
    const int* __restrict__ ptr, const int* __restrict__ rank,
    float* __restrict__ contrib, int M,
    const float* __restrict__ sc, const float* __restrict__ sh)
{
    constexpr int NCG = CTILE / TC;      // cout groups
    constexpr int PPG = 256 / NCG;       // pair groups
    constexpr int PP  = PPG * TP;        // pairs per block
    constexpr int CINC = (CIN > 64) ? 64 : CIN;
    constexpr int NCH  = CIN / CINC;
    constexpr int LOADERS = 256 / PP;
    constexpr int SITER = CINC / 4 / LOADERS;
    constexpr int FTS = PP + 4;          // multiple of 4

    const int k = blockIdx.y;
    __shared__ float Wl[CINC][CTILE];
    __shared__ float ft[CINC][FTS];
    __shared__ int sslot[PP];

    const int cg = threadIdx.x % NCG;
    const int pg = threadIdx.x / NCG;
    const int p0 = pg * TP;
    const int pl = threadIdx.x % PP;
    const int ll = threadIdx.x / PP;

    const int* iin  = in_idx  + (size_t)k * M;
    const int* iout = out_idx + (size_t)k * M;
    const int* rk   = rank    + (size_t)k * M;
    const float* Wk = W + (size_t)k * CIN * WST;

    for (int base = blockIdx.x * PP; base < M; base += gridDim.x * PP) {
        float acc[TP][TC];
        #pragma unroll
        for (int p = 0; p < TP; ++p)
            #pragma unroll
            for (int c = 0; c < TC; ++c) acc[p][c] = 0.f;

        #pragma unroll
        for (int ch = 0; ch < NCH; ++ch) {
            __syncthreads();
            // stage W chunk (restaged per chunk; once when NCH==1)
            for (int i = threadIdx.x; i < CINC * (CTILE / 4); i += 256) {
                int j = i / (CTILE / 4), c4 = (i % (CTILE / 4)) * 4;
                *(float4*)&Wl[j][c4] =
                    *(const float4*)(Wk + (size_t)(ch * CINC + j) * WST + c4);
            }
            int p = base + pl;
            if (p < M) {
                if (ch == 0 && threadIdx.x < PP)
                    sslot[pl] = ptr[iout[p]] + rk[p];
                const float* fr = feats + (size_t)iin[p] * CIN + ch * CINC;
                #pragma unroll
                for (int i = 0; i < SITER; ++i) {
                    int j4 = (ll + i * LOADERS) * 4;
                    float4 v = *(const float4*)(fr + j4);
                    if (GMODE == 2) {
                        float4 s4 = *(const float4*)(sc + ch * CINC + j4);
                        float4 h4 = *(const float4*)(sh + ch * CINC + j4);
                        v.x = fmaxf(fmaf(v.x, s4.x, h4.x), 0.f);
                        v.y = fmaxf(fmaf(v.y, s4.y, h4.y), 0.f);
                        v.z = fmaxf(fmaf(v.z, s4.z, h4.z), 0.f);
                        v.w = fmaxf(fmaf(v.w, s4.w, h4.w), 0.f);
                    }
                    ft[j4 + 0][pl] = v.x;
                    ft[j4 + 1][pl] = v.y;
                    ft[j4 + 2][pl] = v.z;
                    ft[j4 + 3][pl] = v.w;
                }
            }
            __syncthreads();

            #pragma unroll 4
            for (int j = 0; j < CINC; ++j) {
                float fv[TP], wv[TC];
                #pragma unroll
                for (int g = 0; g < TP / 4; ++g)
                    *(float4*)&fv[g * 4] = *(const float4*)&ft[j][p0 + g * 4];
                #pragma unroll
                for (int g = 0; g < TC / 4; ++g)
                    *(float4*)&wv[g * 4] = *(const float4*)&Wl[j][cg * TC + g * 4];
                #pragma unroll
                for (int p = 0; p < TP; ++p)
                    #pragma unroll
                    for (int c = 0; c < TC; ++c)
                        acc[p][c] = fmaf(fv[p], wv[c], acc[p][c]);
            }
        }

        #pragma unroll
        for (int q = 0; q < TP; ++q) {
            if (base + p0 + q < M) {
                size_t s = (size_t)sslot[p0 + q];
                #pragma unroll
                for (int g = 0; g < TC / 4; ++g) {
                    float4 o4;
                    o4.x = acc[q][g * 4 + 0]; o4.y = acc[q][g * 4 + 1];
                    o4.z = acc[q][g * 4 + 2]; o4.w = acc[q][g * 4 + 3];
                    *(float4*)&contrib[s * CTILE + cg * TC + g * 4] = o4;
                }
            }
        }
    }
}

// ---------------- Phase B: segmented sum (+optional fused fp64 BN stats) ---
template <int CSTR, bool STATS>
__global__ __launch_bounds__(256) void phaseB8(
    const float* __restrict__ contrib, const int* __restrict__ ptr,
    float* __restrict__ out, int n, int ostr, int accum,
    double* __restrict__ statsbuf, int sqoff)
{
    float s1 = 0.f, s2 = 0.f;
    int total = n * CSTR;
    for (int idx = blockIdx.x * 256 + threadIdx.x; idx < total; idx += gridDim.x * 256) {
        int o = idx / CSTR, c = idx % CSTR;
        int a = ptr[o], b = ptr[o + 1];
        float acc = accum ? out[(size_t)o * ostr + c] : 0.f;
        for (int s = a; s < b; ++s) acc += contrib[(size_t)s * CSTR + c];
        out[(size_t)o * ostr + c] = acc;
        if (STATS) { s1 += acc; s2 += acc * acc; }
    }
    if constexpr (STATS) {
        __shared__ double l1[256], l2[256];
        l1[threadIdx.x] = (double)s1; l2[threadIdx.x] = (double)s2;
        __syncthreads();
        for (int off = 128; off >= CSTR; off >>= 1) {
            if (threadIdx.x < (unsigned)off) {
                l1[threadIdx.x] += l1[threadIdx.x + off];
                l2[threadIdx.x] += l2[threadIdx.x + off];
            }
            __syncthreads();
        }
        if (threadIdx.x < CSTR) {
            atomicAdd(&statsbuf[threadIdx.x], l1[threadIdx.x]);
            atomicAdd(&statsbuf[sqoff + threadIdx.x], l2[threadIdx.x]);
        }
    }
}

// ---------------- BN helpers (fp64 stats) ----------------
template <int C>
__global__ __launch_bounds__(256) void make_scsh(
    const double* __restrict__ sums, const float* __restrict__ g,
    const float* __restrict__ b, float* __restrict__ sc, float* __restrict__ sh,
    double inv_n)
{
    int c = threadIdx.x;
    if (c < C) {
        double mean = sums[c] * inv_n;
        double var  = sums[C + c] * inv_n - mean * mean;
        float s = g[c] * (float)(1.0 / sqrt(var + (double)EPSc));
        sc[c] = s;
        sh[c] = b[c] - (float)mean * s;
    }
}

template <int C>
__global__ __launch_bounds__(256) void bn_apply_relu_kernel(
    float* __restrict__ x, int n, const double* __restrict__ sums,
    const float* __restrict__ g, const float* __restrict__ b)
{
    const int c = threadIdx.x % C;
    const double inv_n = 1.0 / (double)n;
    double mean = sums[c] * inv_n;
    double var  = sums[C + c] * inv_n - mean * mean;
    float scale = g[c] * (float)(1.0 / sqrt(var + (double)EPSc));
    float shift = b[c] - (float)mean * scale;
    size_t total = (size_t)n * C;
    size_t stride = (size_t)gridDim.x * 256;
    for (size_t i = (size_t)blockIdx.x * 256 + threadIdx.x; i < total; i += stride)
        x[i] = fmaxf(x[i] * scale + shift, 0.f);
}

// ---------------- host-side helpers ----------------
struct Plan { int q, nch; };

static Plan make_plan(long long tot_elems, int K, long long cap, int maxch)
{
    if (cap < 1) cap = 1;
    long long nch0 = (tot_elems + cap - 1) / cap;
    if (nch0 < 1) nch0 = 1;
    if (nch0 > K) nch0 = K;
    int q = (int)((K + nch0 - 1) / nch0);
    int nch = (K + q - 1) / q;
    if (nch > maxch) { q = (K + maxch - 1) / maxch; nch = (K + q - 1) / q; }
    return { q, nch };
}

static void build_csr2d(const int* iout, int* rank, int* bins, int* ptr, int* bsums,
                        int E, int M, int q, int nch, int stride, hipStream_t s)
{
    hipMemsetAsync(bins, 0, (size_t)nch * stride * sizeof(int), s);
    int gb = std::min(2048, (E + 255) / 256);
    hipLaunchKernelGGL(rank2d_kernel, dim3(gb), dim3(256), 0, s, iout, rank, bins, E, M, q, stride);
    int totalbins = nch * stride, nb = totalbins / 1024, bpc = stride / 1024;
    hipLaunchKernelGGL(scan1, dim3(nb), dim3(256), 0, s, bins, ptr, bsums, totalbins);
    hipLaunchKernelGGL(scan2s, dim3(1), dim3(64), 0, s, bsums, bpc, nch);
    hipLaunchKernelGGL(scan3, dim3(nb), dim3(256), 0, s, ptr, bsums, totalbins);
}

// One full layer (no cout split): k-chunked as needed.
template <int CIN, int COUT, int TP, int TC, int GMODE, bool STATS>
static void run_layer(const float* feats, const float* W,
                      const int* iin, const int* iout, float* outp,
                      int M, int K, int n_out, int stride, int maxch,
                      int* bins, int* ptr, int* bsums, int* rank, float* contrib,
                      long long cap, const float* sc, const float* sh,
                      double* statsbuf, hipStream_t s)
{
    constexpr int NCG = COUT / TC;
    constexpr int PP  = (256 / NCG) * TP;
    Plan pl = make_plan((long long)K * M * COUT, K, cap, maxch);
    build_csr2d(iout, rank, bins, ptr, bsums, K * M, M, pl.q, pl.nch, stride, s);
    for (int ch = 0; ch < pl.nch; ++ch) {
        int k0 = ch * pl.q;
        int qc = std::min(pl.q, K - k0);
        dim3 g((M + PP - 1) / PP, qc);
        hipLaunchKernelGGL((phaseA8<CIN, COUT, COUT, TP, TC, GMODE>), g, dim3(256), 0, s,
                           feats, W + (size_t)k0 * CIN * COUT,
                           iin + (size_t)k0 * M, iout + (size_t)k0 * M,
                           ptr + (size_t)ch * stride, rank + (size_t)k0 * M,
                           contrib, M, sc, sh);
        bool last = (ch == pl.nch - 1);
        if (STATS && last)
            hipLaunchKernelGGL((phaseB8<COUT, true>), dim3(2048), dim3(256), 0, s,
                               contrib, ptr + (size_t)ch * stride, outp, n_out, COUT,
                               ch ? 1 : 0, statsbuf, COUT);
        else
            hipLaunchKernelGGL((phaseB8<COUT, false>), dim3(2048), dim3(256), 0, s,
                               contrib, ptr + (size_t)ch * stride, outp, n_out, COUT,
                               ch ? 1 : 0, (double*)nullptr, 0);
    }
}

extern "C" void kernel_launch(void* const* d_in, const int* in_sizes, int n_in,
                              void* d_out, int out_size, void* d_ws, size_t ws_size,
                              hipStream_t stream)
{
    const float* x_feats = (const float*)d_in[0];
    const float* w1a = (const float*)d_in[1];
    const float* w1b = (const float*)d_in[2];
    const float* w1c = (const float*)d_in[3];
    const float* w2  = (const float*)d_in[4];
    const float* w3a = (const float*)d_in[5];
    const float* w3b = (const float*)d_in[6];
    const float* bn1b_g = (const float*)d_in[7];
    const float* bn1b_b = (const float*)d_in[8];
    const float* bn1c_g = (const float*)d_in[9];
    const float* bn1c_b = (const float*)d_in[10];
    const float* bn3a_g = (const float*)d_in[11];
    const float* bn3a_b = (const float*)d_in[12];
    const float* bn3b_g = (const float*)d_in[13];
    const float* bn3b_b = (const float*)d_in[14];
    const int* km1a_in  = (const int*)d_in[15];
    const int* km1a_out = (const int*)d_in[16];
    const int* km1b_in  = (const int*)d_in[17];
    const int* km1b_out = (const int*)d_in[18];
    const int* km1c_in  = (const int*)d_in[19];
    const int* km1c_out = (const int*)d_in[20];
    const int* km2_in   = (const int*)d_in[21];
    const int* km2_out  = (const int*)d_in[22];
    const int* km3a_in  = (const int*)d_in[23];
    const int* km3a_out = (const int*)d_in[24];
    const int* km3b_in  = (const int*)d_in[25];
    const int* km3b_out = (const int*)d_in[26];

    float* out  = (float*)d_out;
    float* x_e1 = out;                       // [N1,32]
    float* x_e2 = out + (size_t)N1c * 32;    // [N2,256]

    // ---- workspace layout (float-element offsets, 16B-aligned) ----
    float* ws = (float*)d_ws;
    float*  poolA  = ws;                        // 10,240,000 (h1 -> h3)
    float*  poolB  = poolA + 10240000;          //  5,120,000 (h2 -> h2b)
    double* dstats = (double*)(poolB + 5120000);//  2,048 doubles (4 layers x 512)
    float*  scsh   = (float*)(dstats + 2048);   //  1,024
    int*    bins   = (int*)(scsh + 1024);       //  819,200
    int*    ptr    = bins + 819200;             //  819,200
    int*    bsums  = ptr + 819200;              //  1,024
    int*    rank   = bsums + 1024;              //  2,500,000
    float*  contrib = (float*)(rank + 2500000);
    const long long FIXED = 10240000LL + 5120000 + 4096 + 1024
                          + 819200 + 819200 + 1024 + 2500000;
    long long cap = (long long)(ws_size / 4) - FIXED - 32;
    if (cap < 1) cap = 1;

    float* h1  = poolA;   // [N1,32]
    float* h3  = poolA;   // [N2,128] (h1 dead by then)
    float* h2  = poolB;   // [N1,32]
    float* h2b = poolB;   // [N2,64]  (h2 dead by then)

    double* dst1b = dstats;
    double* dst1c = dstats + 512;
    double* dst3a = dstats + 1024;
    double* dst3b = dstats + 1536;
    float* sc1b = scsh,       *sh1b = scsh + 32;
    float* sc3a = scsh + 256, *sh3a = scsh + 384;

    hipMemsetAsync(dstats, 0, 2048 * sizeof(double), stream);

    // ---- conv1a (1->32, K=125) + ReLU: scatter (val,k) + W-in-LDS reduce ----
    {
        build_csr2d(km1a_out, rank, bins, ptr, bsums, 125 * 20000, 20000, 125, 1,
                    STRIDE_N1, stream);
        hipLaunchKernelGGL(scatter_1a, dim3(2048), dim3(256), 0, stream,
                           x_feats, km1a_in, km1a_out, ptr, rank, (float2*)contrib,
                           125 * 20000, 20000);
        hipLaunchKernelGGL(phaseB_1a, dim3(2048), dim3(256), 0, stream,
                           (const float2*)contrib, ptr, w1a, h1, N1c);
    }

    // ---- conv1b (32->32, K=125): raw out + fp64 stats; BN fused at next gather
    run_layer<32, 32, 8, 4, 0, true>(h1, w1b, km1b_in, km1b_out, h2, 20000, 125, N1c,
                                     STRIDE_N1, 8, bins, ptr, bsums, rank, contrib,
                                     cap, nullptr, nullptr, dst1b, stream);
    hipLaunchKernelGGL((make_scsh<32>), dim3(1), dim3(256), 0, stream,
                       dst1b, bn1b_g, bn1b_b, sc1b, sh1b, 1.0 / N1c);

    // ---- conv1c (32->32, K=125): BN(h2)+ReLU fused at gather; x_e1 raw + stats
    run_layer<32, 32, 8, 4, 2, true>(h2, w1c, km1c_in, km1c_out, x_e1, 20000, 125, N1c,
                                     STRIDE_N1, 8, bins, ptr, bsums, rank, contrib,
                                     cap, sc1b, sh1b, dst1c, stream);
    hipLaunchKernelGGL((bn_apply_relu_kernel<32>), dim3(2048), dim3(256), 0, stream,
                       x_e1, N1c, dst1c, bn1c_g, bn1c_b);

    // ---- conv2 (32->64, K=27): plain, no activation ----
    run_layer<32, 64, 8, 8, 0, false>(x_e1, w2, km2_in, km2_out, h2b, 30000, 27, N2c,
                                      STRIDE_N2, 10, bins, ptr, bsums, rank, contrib,
                                      cap, nullptr, nullptr, nullptr, stream);

    // ---- conv3a (64->128, K=27): raw out + stats; BN fused at conv3b gather
    run_layer<64, 128, 8, 8, 0, true>(h2b, w3a, km3a_in, km3a_out, h3, 20000, 27, N2c,
                                      STRIDE_N2, 10, bins, ptr, bsums, rank, contrib,
                                      cap, nullptr, nullptr, dst3a, stream);
    hipLaunchKernelGGL((make_scsh<128>), dim3(1), dim3(256), 0, stream,
                       dst3a, bn3a_g, bn3a_b, sc3a, sh3a, 1.0 / N2c);

    // ---- conv3b (128->256, K=27): cout-split into two 128-halves ----
    // One CSR for the layer; per half: phaseA (BN(h3)+ReLU fused) + single phaseB.
    {
        const int M = 20000, K = 27;
        Plan pl = make_plan((long long)K * M * 128, K, cap, 10);
        build_csr2d(km3b_out, rank, bins, ptr, bsums, K * M, M, pl.q, pl.nch,
                    STRIDE_N2, stream);
        constexpr int PP = (256 / (128 / 8)) * 8;   // 128 pairs per block
        for (int half = 0; half < 2; ++half) {
            for (int ch = 0; ch < pl.nch; ++ch) {
                int k0 = ch * pl.q;
                int qc = std::min(pl.q, K - k0);
                dim3 g((M + PP - 1) / PP, qc);
                hipLaunchKernelGGL((phaseA8<128, 128, 256, 8, 8, 2>), g, dim3(256), 0, stream,
                                   h3, w3b + half * 128 + (size_t)k0 * 128 * 256,
                                   km3b_in + (size_t)k0 * M, km3b_out + (size_t)k0 * M,
                                   ptr + (size_t)ch * STRIDE_N2, rank + (size_t)k0 * M,
                                   contrib, M, sc3a, sh3a);
                bool last = (ch == pl.nch - 1);
                if (last)
                    hipLaunchKernelGGL((phaseB8<128, true>), dim3(2048), dim3(256), 0, stream,
                                       contrib, ptr + (size_t)ch * STRIDE_N2,
                                       x_e2 + half * 128, N2c, 256, ch ? 1 : 0,
                                       dst3b + half * 128, 256);
                else
                    hipLaunchKernelGGL((phaseB8<128, false>), dim3(2048), dim3(256), 0, stream,
                                       contrib, ptr + (size_t)ch * STRIDE_N2,
                                       x_e2 + half * 128, N2c, 256, ch ? 1 : 0,
                                       (double*)nullptr, 0);
            }
        }
        hipLaunchKernelGGL((bn_apply_relu_kernel<256>), dim3(2048), dim3(256), 0, stream,
                           x_e2, N2c, dst3b, bn3b_g, bn3b_b);
    }
}